// Round 3
// baseline (545.317 us; speedup 1.0000x reference)
//
#include <hip/hip_runtime.h>

// Trilinear 3D warp: image [1,1,256,256,256] f32, dvf [1,3,256,256,256] f32
// dvf channels: 0=dy, 1=dx, 2=dz. Layout (H,W,D), D innermost.
//
// R2: LDS tile staging. Bottleneck is distinct-cache-line requests/output
// (~3.4 at ~2 cyc/line). Stage a (17,17,41) halo for an (8,8,32) output tile
// into LDS with coalesced loads (~0.5 lines/output), gather from LDS.
// Halo +-4 covers floor(d) in [-4,+4]; rarer displacements (P ~2e-4/voxel)
// take an exec-masked global-gather fallback (required for correctness:
// N(0,1) is unbounded).
// Fractions use the CLIPPED low corner (matches reference exactly).

constexpr int H = 256, W = 256, D = 256;
constexpr int N = H * W * D;

constexpr int TY = 8, TX = 8, TZ = 32;          // output tile
constexpr int HY = TY + 9, HX = TX + 9, HZ = TZ + 9;  // halo: 17 x 17 x 41
constexpr int HALO_N = HY * HX * HZ;            // 11849 floats = 47.4 KB

__global__ __launch_bounds__(256, 3) void warp3d_kernel(
    const float* __restrict__ img,
    const float* __restrict__ dvf,
    float* __restrict__ out)
{
    __shared__ float tile[HALO_N];

    const int tid = threadIdx.x;
    const int b = blockIdx.x;
    // blocks: 32 y-tiles x 32 x-tiles x 8 z-tiles, z innermost
    const int bz = b & 7;
    const int bx = (b >> 3) & 31;
    const int by = b >> 8;
    const int ybase = by * TY, xbase = bx * TX, zbase = bz * TZ;
    const int y_lo = ybase - 4, x_lo = xbase - 4, z_lo = zbase - 4;

    // ---- stage halo (coalesced: consecutive e -> consecutive gz) ----
    for (int e = tid; e < HALO_N; e += 256) {
        const int hy = e / (HX * HZ);
        const int r  = e - hy * (HX * HZ);
        const int hx = r / HZ;
        const int hz = r - hx * HZ;
        // clamp address only; out-of-range halo cells are never read back
        const int gy = min(max(y_lo + hy, 0), H - 1);
        const int gx = min(max(x_lo + hx, 0), W - 1);
        const int gz = min(max(z_lo + hz, 0), D - 1);
        tile[e] = img[(gy << 16) | (gx << 8) | gz];
    }
    __syncthreads();

    // lane -> (x,z) within tile; iterate y
    const int lz = tid & (TZ - 1);
    const int lx = (tid >> 5) & (TX - 1);
    const int gx = xbase + lx;
    const int gz = zbase + lz;

    for (int v = 0; v < TY; ++v) {
        const int gy = ybase + v;
        const int i = (gy << 16) | (gx << 8) | gz;

        const float dy = dvf[i];
        const float dx = dvf[i + N];
        const float dz = dvf[i + 2 * N];

        const float ny = (float)gy + dy;
        const float nx = (float)gx + dx;
        const float nz = (float)gz + dz;

        const int iy = (int)floorf(ny);
        const int ix = (int)floorf(nx);
        const int iz = (int)floorf(nz);

        const int y0 = min(max(iy,     0), H - 1);
        const int y1 = min(max(iy + 1, 0), H - 1);
        const int x0 = min(max(ix,     0), W - 1);
        const int x1 = min(max(ix + 1, 0), W - 1);
        const int z0 = min(max(iz,     0), D - 1);
        const int z1 = min(max(iz + 1, 0), D - 1);

        const float yd = ny - (float)y0;
        const float xd = nx - (float)x0;
        const float zd = nz - (float)z0;

        float c000, c001, c010, c011, c100, c101, c110, c111;

        const bool in_lds =
            (y0 >= y_lo) & (y1 <= y_lo + HY - 1) &
            (x0 >= x_lo) & (x1 <= x_lo + HX - 1) &
            (z0 >= z_lo) & (z1 <= z_lo + HZ - 1);

        if (in_lds) {
            const int ly0 = y0 - y_lo, ly1 = y1 - y_lo;
            const int lx0 = x0 - x_lo, lx1 = x1 - x_lo;
            const int lz0 = z0 - z_lo, lz1 = z1 - z_lo;
            const int r00 = (ly0 * HX + lx0) * HZ;
            const int r01 = (ly0 * HX + lx1) * HZ;
            const int r10 = (ly1 * HX + lx0) * HZ;
            const int r11 = (ly1 * HX + lx1) * HZ;
            c000 = tile[r00 + lz0]; c001 = tile[r00 + lz1];
            c010 = tile[r01 + lz0]; c011 = tile[r01 + lz1];
            c100 = tile[r10 + lz0]; c101 = tile[r10 + lz1];
            c110 = tile[r11 + lz0]; c111 = tile[r11 + lz1];
        } else {
            // rare fallback: direct global gather with clipped indices
            const int g00 = (y0 << 16) | (x0 << 8);
            const int g01 = (y0 << 16) | (x1 << 8);
            const int g10 = (y1 << 16) | (x0 << 8);
            const int g11 = (y1 << 16) | (x1 << 8);
            c000 = img[g00 + z0]; c001 = img[g00 + z1];
            c010 = img[g01 + z0]; c011 = img[g01 + z1];
            c100 = img[g10 + z0]; c101 = img[g10 + z1];
            c110 = img[g11 + z0]; c111 = img[g11 + z1];
        }

        const float omz = 1.0f - zd;
        const float c00 = c000 * omz + c001 * zd;
        const float c01 = c010 * omz + c011 * zd;
        const float c10 = c100 * omz + c101 * zd;
        const float c11 = c110 * omz + c111 * zd;

        const float omx = 1.0f - xd;
        const float c0 = c00 * omx + c01 * xd;
        const float c1 = c10 * omx + c11 * xd;

        out[i] = c0 * (1.0f - yd) + c1 * yd;
    }
}

extern "C" void kernel_launch(void* const* d_in, const int* in_sizes, int n_in,
                              void* d_out, int out_size, void* d_ws, size_t ws_size,
                              hipStream_t stream) {
    const float* img = (const float*)d_in[0];
    const float* dvf = (const float*)d_in[1];
    float* out = (float*)d_out;

    dim3 block(256);
    dim3 grid((H / TY) * (W / TX) * (D / TZ));  // 8192 blocks
    warp3d_kernel<<<grid, block, 0, stream>>>(img, dvf, out);
}